// Round 1
// baseline (651.491 us; speedup 1.0000x reference)
//
#include <hip/hip_runtime.h>
#include <hip/hip_bf16.h>

typedef __hip_bfloat16 bf16;
typedef __attribute__((ext_vector_type(8))) short bf16x8;
typedef __attribute__((ext_vector_type(4))) float f32x4;

#define S_LEN   2048
#define HIDDEN  5120
#define NHEADS  16
#define QLORA   1536
#define KVLORA  512
#define QKD     192
#define VD      128
#define QN      (NHEADS*QKD)          /* 3072 */
#define KVN     (NHEADS*(128+VD))     /* 4096 */
#define QCKN    2112                  /* 1536 qa | 512 ckv | 64 kpe */
#define QCKP    2304                  /* padded to 9*256 for 256-tile GEMM */
#define SM_SCALE 0.07216878364870322f /* 192^-0.5 */

__device__ __forceinline__ f32x4 mfma16(bf16x8 a, bf16x8 b, f32x4 c) {
  return __builtin_amdgcn_mfma_f32_16x16x32_bf16(a, b, c, 0, 0, 0);
}
__device__ __forceinline__ void g2l16(const void* g, void* l) {
  __builtin_amdgcn_global_load_lds((const __attribute__((address_space(1))) void*)g,
                                   (__attribute__((address_space(3))) void*)l, 16, 0, 0);
}
__device__ __forceinline__ bf16x8 ld8(const bf16* p) { return *(const bf16x8*)p; }

// raw barrier: does NOT drain vmcnt (the whole point of the counted pipeline).
// sched_barrier(0) pins phase boundaries so the compiler can't merge phases.
__device__ __forceinline__ void bar() {
  __builtin_amdgcn_sched_barrier(0);
  __builtin_amdgcn_s_barrier();
  __builtin_amdgcn_sched_barrier(0);
}
#define VMCNT(n) asm volatile("s_waitcnt vmcnt(" #n ")" ::: "memory")

// -------- init: zero split-K accumulators + w1_b N-pad rows ----------
__global__ void init_k(float4* __restrict__ qa_ckv, int n0,
                       float4* __restrict__ q_f, int n1,
                       float4* __restrict__ w1pad, int n2)
{
  int i = blockIdx.x * 256 + threadIdx.x;
  const float4 z = (float4){0.f, 0.f, 0.f, 0.f};
  if (i < n0) { qa_ckv[i] = z; return; }
  if ((i -= n0) < n1) { q_f[i] = z; return; }
  if ((i -= n1) < n2) w1pad[i] = z;
}

// ---------------- fused fp32 -> bf16 cast over 5 weight segments ----------------
__global__ void cvt_multi(const float* s0, bf16* d0, int n0,
                          const float* s1, bf16* d1, int n1,
                          const float* s2, bf16* d2, int n2,
                          const float* s3, bf16* d3, int n3,
                          const float* s4, bf16* d4, int n4s)
{
  int i = blockIdx.x * 256 + threadIdx.x;
  const float* s; bf16* d;
  if (i < n0) { s = s0; d = d0; }
  else if ((i -= n0) < n1) { s = s1; d = d1; }
  else if ((i -= n1) < n2) { s = s2; d = d2; }
  else if ((i -= n2) < n3) { s = s3; d = d3; }
  else if ((i -= n3) < n4s) { s = s4; d = d4; }
  else return;
  const float4 v = ((const float4*)s)[i];
  union { bf16 b[4]; unsigned long long u; } pk;
  pk.b[0] = __float2bfloat16(v.x);
  pk.b[1] = __float2bfloat16(v.y);
  pk.b[2] = __float2bfloat16(v.z);
  pk.b[3] = __float2bfloat16(v.w);
  *(unsigned long long*)(d + (size_t)i * 4) = pk.u;
}

// ---------------- RMSNorm (fp32 in, bf16 out), one block per row ----------------
__global__ void rmsnorm_k(const float* __restrict__ in, int istride, int C,
                          const float* __restrict__ w,
                          bf16* __restrict__ out, int ostride)
{
  const int row = blockIdx.x;
  const float* x = in + (size_t)row * istride;
  float ss = 0.f;
  for (int c = threadIdx.x; c < C; c += 256) { float v = x[c]; ss += v * v; }
  #pragma unroll
  for (int m = 32; m >= 1; m >>= 1) ss += __shfl_xor(ss, m, 64);
  __shared__ float red[4];
  if ((threadIdx.x & 63) == 0) red[threadIdx.x >> 6] = ss;
  __syncthreads();
  ss = red[0] + red[1] + red[2] + red[3];
  const float sc = rsqrtf(ss / (float)C + 1e-6f);
  bf16* o = out + (size_t)row * ostride;
  for (int c = threadIdx.x; c < C; c += 256)
    o[c] = __float2bfloat16(x[c] * sc * w[c]);
}

// ---- fused dual RMSNorm: rows 0..S-1 -> qa (C=1536), rows S..2S-1 -> ckv (C=512)
__global__ void rmsnorm2_k(const float* __restrict__ qackv,
                           const float* __restrict__ wq, const float* __restrict__ wk,
                           bf16* __restrict__ qa_n, bf16* __restrict__ ckv_n)
{
  const int r = blockIdx.x;
  const bool is_q = r < S_LEN;
  const int row = is_q ? r : r - S_LEN;
  const int C = is_q ? QLORA : KVLORA;
  const float* x = qackv + (size_t)row * QCKP + (is_q ? 0 : QLORA);
  const float* w = is_q ? wq : wk;
  bf16* o = (is_q ? qa_n + (size_t)row * QLORA : ckv_n + (size_t)row * KVLORA);
  float ss = 0.f;
  for (int c = threadIdx.x; c < C; c += 256) { float v = x[c]; ss += v * v; }
  #pragma unroll
  for (int m = 32; m >= 1; m >>= 1) ss += __shfl_xor(ss, m, 64);
  __shared__ float red[4];
  if ((threadIdx.x & 63) == 0) red[threadIdx.x >> 6] = ss;
  __syncthreads();
  ss = red[0] + red[1] + red[2] + red[3];
  const float sc = rsqrtf(ss / (float)C + 1e-6f);
  for (int c = threadIdx.x; c < C; c += 256)
    o[c] = __float2bfloat16(x[c] * sc * w[c]);
}

// =====================================================================
// 8-phase 256x256 NT GEMM (T1 xcd-swizzle, T2 lds-xor-swizzle, T3/T4
// 4-phase-per-K-tile counted-vmcnt pipeline, T5 setprio).
// C[2048, NT*256] (+)= A[2048,K] @ Bt[NT*256,K]^T, split-K over z chunks.
// 512 thr = 8 waves (2M x 4N), per-wave C 128x64, BK=64, LDS 128 KiB.
// Stage ring: tile t reads A in P1/P2, B in P1/P3; stages: B(t+1)@P1/P2
// (other slot, B-free since P3(t-1)), A(t+2)@P3/P4 (own slot, A-free
// since P2(t)). vmcnt(4) at P4 leaves exactly the two A(t+2) stages in
// flight => tile t+1 fully landed. Never vmcnt(0) in the loop.
// LDS swizzle: byte-in-row(128B) ^= (row&7)<<4, applied on the g2l
// SOURCE (pre-swizzled global address, LDS dest linear) and on the
// ds_read address => b128 frag reads hit the 8-cyc floor.
// =====================================================================
struct GP {
  const bf16* A; const bf16* Bt; float* C;
  const float* resid;
  float rscale;
  int lda;    // K total (elements)
  int NT;     // N / 256
  int klen;   // K per z chunk
  int N;      // C row stride
  int flags;  // 1 = atomic (split-K), 2 = residual add
};

#define LDA8(m, ks) ld8((const bf16*)(ldsw + s + wa_off + (((m) * 2048 + fx0) ^ ((ks) * 64))))
#define LDB8(n, ks) ld8((const bf16*)(ldsw + s + 32768 + wb_off + (((n) * 2048 + fx0) ^ ((ks) * 64))))

#define PH(M0, N0)                                                            \
  do {                                                                        \
    __builtin_amdgcn_s_setprio(1);                                            \
    _Pragma("unroll") for (int mm = 0; mm < 4; ++mm)                          \
      _Pragma("unroll") for (int nn = 0; nn < 2; ++nn) {                      \
        acc[(M0)+mm][(N0)+nn] =                                               \
            mfma16(af[0][(M0)+mm], bq[0][(N0)+nn], acc[(M0)+mm][(N0)+nn]);    \
        acc[(M0)+mm][(N0)+nn] =                                               \
            mfma16(af[1][(M0)+mm], bq[1][(N0)+nn], acc[(M0)+mm][(N0)+nn]);    \
      }                                                                       \
    __builtin_amdgcn_s_setprio(0);                                            \
  } while (0)

__global__ __launch_bounds__(512, 2)
void gemm8p(GP p0, GP p1, int nb0, int q8)
{
  __shared__ char lds[131072];
  // T1: bijective xcd swizzle (total = q8*8 always divisible by 8)
  const int orig = blockIdx.x;
  int wg = (orig & 7) * q8 + (orig >> 3);
  GP p = p0;
  if (wg >= nb0) { p = p1; wg -= nb0; }
  const int per = p.NT << 3;
  const int zi = wg / per;
  const int tb = wg - zi * per;
  const int bm = (tb & 7) << 8;
  const int bn = (tb >> 3) << 8;
  const int lda = p.lda;
  const int nt = p.klen >> 6;
  const int kb = zi * p.klen;

  const int tid = threadIdx.x;
  const int lane = tid & 63;
  const int l15 = lane & 15, quad = lane >> 4;
  const int waveu = __builtin_amdgcn_readfirstlane(tid >> 6);
  const int wa = waveu >> 2, wn4 = waveu & 3, wb = wn4 >> 1;
  const int woff = waveu << 10;
  const int wa_off = wa << 14;
  const int wb_off = (wb << 14) + ((wn4 & 1) << 13);

  // staging map: thread covers LDS linear bytes tid*16 (+8192 on call 1);
  // source address pre-swizzled: col slot ^= row&7
  const int rb = tid >> 3;                                  // row 0..63
  const int celem = (((tid & 7) << 4) ^ ((rb & 7) << 4)) >> 1;
  // frag read offset: row=l15 within frag, byte-in-row (quad*16)^hash
  const int fx0 = l15 * 128 + (((quad << 4) ^ ((l15 & 7) << 4)));

  const bf16* a0 = p.A + (size_t)(bm + rb) * lda + kb + celem;
  const bf16* a1 = a0 + (size_t)128 * lda;
  const bf16* b0 = p.Bt + (size_t)(bn + rb) * lda + kb + celem;
  const bf16* b1 = b0 + (size_t)128 * lda;
  const size_t lda64 = (size_t)64 * lda;
  char* ldsw = (char*)lds;

  auto stA = [&](int t, int h) {
    const int ts = t < nt ? t : nt - 1;        // clamp: tail re-stages, harmless
    const bf16* sp = (h ? a1 : a0) + ts * 64;
    char* d = ldsw + ((t & 1) << 16) + (h << 14) + woff;
    g2l16(sp, d);
    g2l16(sp + lda64, d + 8192);
  };
  auto stB = [&](int t, int h) {
    const int ts = t < nt ? t : nt - 1;
    const bf16* sp = (h ? b1 : b0) + ts * 64;
    char* d = ldsw + ((t & 1) << 16) + 32768 + (h << 14) + woff;
    g2l16(sp, d);
    g2l16(sp + lda64, d + 8192);
  };

  f32x4 acc[8][4];
  #pragma unroll
  for (int m = 0; m < 8; ++m)
    #pragma unroll
    for (int n = 0; n < 4; ++n) acc[m][n] = (f32x4){0.f, 0.f, 0.f, 0.f};
  bf16x8 af[2][8], bq[2][4];

  // prologue: tile0 full + tile1 A; leave tile1.A (4 loads) in flight
  stA(0, 0); stA(0, 1); stB(0, 0); stB(0, 1); stA(1, 0); stA(1, 1);
  VMCNT(4);
  bar();

  for (int t = 0; t < nt; ++t) {
    const int s = (t & 1) << 16;
    // ---- P1: stage B(t+1).h0 | read A[m0-3], B[n0-1] | mfma m0-3 x n0-1
    stB(t + 1, 0);
    #pragma unroll
    for (int ks = 0; ks < 2; ++ks) {
      #pragma unroll
      for (int m = 0; m < 4; ++m) af[ks][m] = LDA8(m, ks);
      #pragma unroll
      for (int n = 0; n < 2; ++n) bq[ks][n] = LDB8(n, ks);
    }
    bar(); PH(0, 0); bar();
    // ---- P2: stage B(t+1).h1 | read A[m4-7] | mfma m4-7 x n0-1
    stB(t + 1, 1);
    #pragma unroll
    for (int ks = 0; ks < 2; ++ks)
      #pragma unroll
      for (int m = 4; m < 8; ++m) af[ks][m] = LDA8(m, ks);
    bar(); PH(4, 0); bar();
    // ---- P3: stage A(t+2).h0 | read B[n2-3] | mfma m4-7 x n2-3
    stA(t + 2, 0);
    #pragma unroll
    for (int ks = 0; ks < 2; ++ks)
      #pragma unroll
      for (int n = 2; n < 4; ++n) bq[ks][n] = LDB8(n, ks);
    bar(); PH(4, 2); bar();
    // ---- P4: stage A(t+2).h1 | mfma m0-3 x n2-3 | counted vmcnt
    stA(t + 2, 1);
    bar(); PH(0, 2);
    VMCNT(4);                 // leaves only A(t+2) stages in flight
    bar();
  }
  VMCNT(0);                   // drain tail-clamped stages before LDS dies

  // ---- epilogue: C[row = bm+wa*128+m*16+quad*4+r][col = bn+wn4*64+n*16+l15]
  const int rowb = bm + wa * 128 + quad * 4;
  const int colb = bn + wn4 * 64 + l15;
  const bool at = (p.flags & 1) != 0;
  const bool rs = (p.flags & 2) != 0;
  #pragma unroll
  for (int m = 0; m < 8; ++m)
    #pragma unroll
    for (int n = 0; n < 4; ++n) {
      const int col = colb + n * 16;
      #pragma unroll
      for (int r = 0; r < 4; ++r) {
        const int row = rowb + m * 16 + r;
        float v = acc[m][n][r];
        const size_t idx = (size_t)row * p.N + col;
        if (rs) v += p.resid[idx] * p.rscale;
        if (at) unsafeAtomicAdd(&p.C[idx], v);
        else    p.C[idx] = v;
      }
    }
}

// ---------------- RoPE + assemble q/k (bf16 for attn, fp32 k out) ----------------
__global__ void rope_assemble_k(
    const float* __restrict__ q,      // [S, 3072]
    const float* __restrict__ qackv,  // [S, 2304] (kpe at col 2048)
    const float* __restrict__ kv,     // [S, 4096]
    const int*   __restrict__ pos,    // [S]
    float* __restrict__ k_out,        // [16,S,192]
    bf16*  __restrict__ q_bf,         // [16,S,192]
    bf16*  __restrict__ k_bf)         // [16,S,192]
{
  const int s = blockIdx.x;
  const int t = threadIdx.x;
  __shared__ float cs[32], sn[32], kpe[64];
  const float p = (float)pos[s];
  if (t < 32) {
    const float inv = powf(10000.0f, -((float)(2 * t)) / 64.0f);
    const float f = p * inv;
    float si, c;
    sincosf(f, &si, &c);
    cs[t] = c; sn[t] = si;
    const float r0v = qackv[(size_t)s * QCKP + 2048 + 2 * t];
    const float r1v = qackv[(size_t)s * QCKP + 2048 + 2 * t + 1];
    kpe[t]      = r0v * c - r1v * si;
    kpe[32 + t] = r1v * c + r0v * si;
  }
  __syncthreads();
  for (int i = t; i < NHEADS * 128; i += 256) {
    const int h = i >> 7, d = i & 127;
    const size_t o = ((size_t)h * S_LEN + s) * QKD + d;
    const float kn = kv[(size_t)s * KVN + h * 256 + d];
    k_out[o] = kn;
    k_bf[o] = __float2bfloat16(kn);
    q_bf[o] = __float2bfloat16(q[(size_t)s * QN + h * QKD + d]);
  }
  for (int i = t; i < NHEADS * 32; i += 256) {
    const int h = i >> 5, jj = i & 31;
    const float r0v = q[(size_t)s * QN + h * QKD + 128 + 2 * jj];
    const float r1v = q[(size_t)s * QN + h * QKD + 128 + 2 * jj + 1];
    const float c = cs[jj], si = sn[jj];
    const size_t o = ((size_t)h * S_LEN + s) * QKD + 128;
    q_bf[o + jj]      = __float2bfloat16(r0v * c - r1v * si);
    q_bf[o + 32 + jj] = __float2bfloat16(r1v * c + r0v * si);
  }
  for (int i = t; i < NHEADS * 64; i += 256) {
    const int h = i >> 6, jj = i & 63;
    const float v = kpe[jj];
    const size_t o = ((size_t)h * S_LEN + s) * QKD + 128 + jj;
    k_out[o] = v;
    k_bf[o] = __float2bfloat16(v);
  }
}

// ---------------- V: fp32 out + bf16 transpose [16][128][2048] ----------------
__global__ void v_transpose_k(const float* __restrict__ kv,
                              float* __restrict__ v_out,
                              bf16* __restrict__ vt_bf)
{
  const int h = blockIdx.x, st = blockIdx.y, dt = blockIdx.z;
  __shared__ float tile[32][33];
  const int tx = threadIdx.x & 31;
  const int ty = (threadIdx.x >> 5) * 4;
  const int s0 = st * 32, d0 = dt * 32;
  #pragma unroll
  for (int r = 0; r < 4; r++) {
    const int sl = ty + r;
    const float v = kv[(size_t)(s0 + sl) * KVN + h * 256 + 128 + d0 + tx];
    v_out[((size_t)h * S_LEN + s0 + sl) * VD + d0 + tx] = v;
    tile[sl][tx] = v;
  }
  __syncthreads();
  #pragma unroll
  for (int r = 0; r < 4; r++) {
    const int dl = ty + r;
    vt_bf[((size_t)h * VD + d0 + dl) * S_LEN + s0 + tx] = __float2bfloat16(tile[tx][dl]);
  }
}

// ---------------- causal flash attention (v4, unchanged) ----------------
__global__ __launch_bounds__(256, 3)
void attn_k(const bf16* __restrict__ qb, const bf16* __restrict__ kb,
            const bf16* __restrict__ vt, bf16* __restrict__ aout)
{
  const int head = blockIdx.y;
  const int qt = (head < 8) ? blockIdx.x : (gridDim.x - 1 - blockIdx.x);
  const int wave = threadIdx.x >> 6, lane = threadIdx.x & 63;
  const int l15 = lane & 15, quad = lane >> 4;
  const int r0 = qt * 64 + wave * 16;

  const bf16* qh = qb + (size_t)head * S_LEN * QKD;
  const bf16* kh = kb + (size_t)head * S_LEN * QKD;
  const bf16* vh = vt + (size_t)head * VD * S_LEN;

  __shared__ bf16 Ks[6 * 64 * 32];
  __shared__ bf16 Vs[128 * 72];
  __shared__ bf16 Plds[4][16][72];

  const int tid = threadIdx.x;
  const int srow = wave * 16 + (lane >> 2);
  const int scol = (lane & 3) * 8;
  const bf16* ksrc = kh + (size_t)srow * QKD + scol;
  bf16* kdst = Ks + srow * 32 + scol;
  const int vrow = tid >> 1;
  const int vcol = (tid & 1) * 32;
  const bf16* vsrc = vh + (size_t)vrow * S_LEN + vcol;
  bf16* vdst = Vs + vrow * 72 + vcol;

  bf16x8 qf[6];
  #pragma unroll
  for (int c = 0; c < 6; ++c)
    qf[c] = ld8(qh + (size_t)(r0 + l15) * QKD + c * 32 + quad * 8);

  f32x4 O[8];
  #pragma unroll
  for (int d = 0; d < 8; ++d) O[d] = (f32x4){0.f, 0.f, 0.f, 0.f};
  float mrow[4] = {-1e30f, -1e30f, -1e30f, -1e30f};
  float lrow[4] = {0.f, 0.f, 0.f, 0.f};

  bf16x8 kreg[6], vreg[4];
  #pragma unroll
  for (int c = 0; c < 6; ++c) kreg[c] = ld8(ksrc + c * 32);
  #pragma unroll
  for (int c = 0; c < 4; ++c) vreg[c] = ld8(vsrc + c * 8);

  for (int j = 0; j <= qt; ++j) {
    __syncthreads();
    #pragma unroll
    for (int c = 0; c < 6; ++c) *(bf16x8*)(kdst + c * 2048) = kreg[c];
    #pragma unroll
    for (int c = 0; c < 4; ++c) *(bf16x8*)(vdst + c * 8) = vreg[c];
    __syncthreads();
    if (j < qt) {
      const bf16* src = ksrc + (size_t)(j + 1) * 64 * QKD;
      #pragma unroll
      for (int c = 0; c < 6; ++c) kreg[c] = ld8(src + c * 32);
      const bf16* vs2 = vsrc + (size_t)(j + 1) * 64;
      #pragma unroll
      for (int c = 0; c < 4; ++c) vreg[c] = ld8(vs2 + c * 8);
    }
    const int kc = j * 64;

    f32x4 S[4];
    #pragma unroll
    for (int nt = 0; nt < 4; ++nt) S[nt] = (f32x4){0.f, 0.f, 0.f, 0.f};
    #pragma unroll
    for (int c = 0; c < 6; ++c) {
      #pragma unroll
      for (int nt = 0; nt < 4; ++nt) {
        const bf16x8 kf = ld8(Ks + c * 2048 + (nt * 16 + l15) * 32 + quad * 8);
        S[nt] = mfma16(qf[c], kf, S[nt]);
      }
    }

    float mnew[4] = {-1e30f, -1e30f, -1e30f, -1e30f};
    if (j == qt) {
      #pragma unroll
      for (int nt = 0; nt < 4; ++nt) {
        const int col = kc + nt * 16 + l15;
        #pragma unroll
        for (int r = 0; r < 4; r++) {
          const int row = r0 + quad * 4 + r;
          const float v = (col <= row) ? S[nt][r] * SM_SCALE : -1e30f;
          S[nt][r] = v;
          mnew[r] = fmaxf(mnew[r], v);
        }
      }
    } else {
      #pragma unroll
      for (int nt = 0; nt < 4; ++nt)
        #pragma unroll
        for (int r = 0; r < 4; r++) {
          const float v = S[nt][r] * SM_SCALE;
          S[nt][r] = v;
          mnew[r] = fmaxf(mnew[r], v);
        }
    }
    #pragma unroll
    for (int m = 8; m >= 1; m >>= 1)
      #pragma unroll
      for (int r = 0; r < 4; r++)
        mnew[r] = fmaxf(mnew[r], __shfl_xor(mnew[r], m, 64));
    float alpha[4], ladd[4] = {0.f, 0.f, 0.f, 0.f};
    #pragma unroll
    for (int r = 0; r < 4; r++) {
      const float mi = fmaxf(mrow[r], mnew[r]);
      alpha[r] = __expf(mrow[r] - mi);
      mrow[r] = mi;
    }
    #pragma unroll
    for (int nt = 0; nt < 4; ++nt)
      #pragma unroll
      for (int r = 0; r < 4; r++) {
        const float pv = __expf(S[nt][r] - mrow[r]);
        S[nt][r] = pv;
        ladd[r] += pv;
      }
    #pragma unroll
    for (int m = 8; m >= 1; m >>= 1)
      #pragma unroll
      for (int r = 0; r < 4; r++) ladd[r] += __shfl_xor(ladd[r], m, 64);
    #pragma unroll
    for (int r = 0; r < 4; r++) lrow[r] = lrow[r] * alpha[r] + ladd[r];
    #pragma unroll
    for (int d = 0; d < 8; ++d)
      #pragma unroll
      for (int r = 0; r < 4; r++) O[d][r] *= alpha[r];

    #pragma unroll
    for (int nt = 0; nt < 4; ++nt)
      #pragma unroll
      for (int r = 0; r < 4; r++)
        Plds[wave][quad * 4 + r][nt * 16 + l15] = __float2bfloat16(S[nt][r]);

    #pragma unroll
    for (int kt = 0; kt < 2; ++kt) {
      const bf16x8 pf = ld8(&Plds[wave][l15][kt * 32 + quad * 8]);
      #pragma unroll
      for (int dt = 0; dt < 8; ++dt) {
        const bf16x8 vf = ld8(Vs + (dt * 16 + l15) * 72 + kt * 32 + quad * 8);
        O[dt] = mfma16(pf, vf, O[dt]);
      }
    }
  }

  #pragma unroll
  for (int dt = 0; dt < 8; ++dt) {
    const int col = head * VD + dt * 16 + l15;
    #pragma unroll
    for (int r = 0; r < 4; r++) {
      const int row = r0 + quad * 4 + r;
      aout[(size_t)row * (NHEADS * VD) + col] = __float2bfloat16(O[dt][r] / lrow[r]);
    }
  }
}

// ---------------- host orchestration ----------------
extern "C" void kernel_launch(void* const* d_in, const int* in_sizes, int n_in,
                              void* d_out, int out_size, void* d_ws, size_t ws_size,
                              hipStream_t stream)
{
  const float* hs      = (const float*)d_in[0];
  const int*   pos     = (const int*)  d_in[1];
  const float* ln_w    = (const float*)d_in[3];
  const float* wq_a    = (const float*)d_in[4];
  const float* q_a_ln  = (const float*)d_in[5];
  const float* wq_b    = (const float*)d_in[6];
  const float* wkv_a   = (const float*)d_in[7];
  const float* kv_a_ln = (const float*)d_in[8];
  const float* wkv_b   = (const float*)d_in[9];
  const float* wo      = (const float*)d_in[10];

  float* out_hidden = (float*)d_out;
  float* out_k = out_hidden + (size_t)S_LEN * HIDDEN;
  float* out_v = out_k + (size_t)NHEADS * S_LEN * QKD;

  char* ws = (char*)d_ws;
  size_t off = 0;
  auto alloc = [&](size_t bytes) { char* p = ws + off; off += (bytes + 255) & ~255ULL; return p; };

  bf16* h_b     = (bf16*)alloc((size_t)S_LEN * HIDDEN * 2);
  bf16* w1_b    = (bf16*)alloc((size_t)QCKP * HIDDEN * 2);     // padded N=2304
  bf16* wqb_b   = (bf16*)alloc((size_t)QN * QLORA * 2);
  bf16* wkvb_b  = (bf16*)alloc((size_t)KVN * KVLORA * 2);
  bf16* wo_b    = (bf16*)alloc((size_t)HIDDEN * (NHEADS * VD) * 2);
  float* qa_ckv = (float*)alloc((size_t)S_LEN * QCKP * 4);     // stride 2304
  float* q_f    = (float*)alloc((size_t)S_LEN * QN * 4);
  bf16* qa_n    = (bf16*)alloc((size_t)S_LEN * QLORA * 2);
  bf16* ckv_n   = (bf16*)alloc((size_t)S_LEN * KVLORA * 2);
  float* kv_f   = (float*)alloc((size_t)S_LEN * KVN * 4);
  bf16* q_bf    = (bf16*)alloc((size_t)NHEADS * S_LEN * QKD * 2);
  bf16* k_bf    = (bf16*)alloc((size_t)NHEADS * S_LEN * QKD * 2);
  bf16* vt_bf   = (bf16*)alloc((size_t)NHEADS * VD * S_LEN * 2);
  bf16* attn_b  = h_b;   // alias: h_b dead after gemm1, attn written after

  {
    const int n0 = (int)((size_t)S_LEN * QCKP / 4);
    const int n1 = (int)((size_t)S_LEN * QN / 4);
    const int n2 = (int)((size_t)(QCKP - QCKN) * HIDDEN * 2 / 16);
    const int tot = n0 + n1 + n2;
    init_k<<<(tot + 255) / 256, 256, 0, stream>>>(
        (float4*)qa_ckv, n0, (float4*)q_f, n1,
        (float4*)(w1_b + (size_t)QCKN * HIDDEN), n2);
  }

  {
    const int n0 = (QLORA * HIDDEN) / 4;
    const int n1 = ((QCKN - QLORA) * HIDDEN) / 4;
    const int n2 = (QN * QLORA) / 4;
    const int n3 = (KVN * KVLORA) / 4;
    const int n4s = (HIDDEN * NHEADS * VD) / 4;
    const int tot = n0 + n1 + n2 + n3 + n4s;
    cvt_multi<<<(tot + 255) / 256, 256, 0, stream>>>(
        wq_a, w1_b, n0,
        wkv_a, w1_b + (size_t)QLORA * HIDDEN, n1,
        wq_b, wqb_b, n2,
        wkv_b, wkvb_b, n3,
        wo, wo_b, n4s);
  }

  rmsnorm_k<<<S_LEN, 256, 0, stream>>>(hs, HIDDEN, HIDDEN, ln_w, h_b, HIDDEN);

  // gemm1: [qa|ckv|pad] = h @ w1^T   N=2304, split-K z=5 -> 360 blocks, atomic
  {
    GP g1 = {h_b, w1_b, qa_ckv, nullptr, 0.f, HIDDEN, 9, 1024, QCKP, 1};
    gemm8p<<<dim3(360), 512, 0, stream>>>(g1, g1, 360, 45);
  }

  rmsnorm2_k<<<2 * S_LEN, 256, 0, stream>>>(qa_ckv, q_a_ln, kv_a_ln, qa_n, ckv_n);

  // gemm2 (q, z=2, atomic) + gemm3 (kv, z=1) merged: 192+128 = 320 blocks
  {
    GP g2 = {qa_n, wqb_b, q_f, nullptr, 0.f, QLORA, 12, 768, QN, 1};
    GP g3 = {ckv_n, wkvb_b, kv_f, nullptr, 0.f, KVLORA, 16, 512, KVN, 0};
    gemm8p<<<dim3(320), 512, 0, stream>>>(g2, g3, 192, 40);
  }

  rope_assemble_k<<<S_LEN, 256, 0, stream>>>(q_f, qa_ckv, kv_f, pos, out_k, q_bf, k_bf);
  v_transpose_k<<<dim3(NHEADS, S_LEN / 32, VD / 32), 256, 0, stream>>>(kv_f, out_v, vt_bf);

  attn_k<<<dim3(S_LEN / 64, NHEADS), 256, 0, stream>>>(q_bf, k_bf, vt_bf, attn_b);

  // gemm4: out = attn @ wo^T + hs*0.125   N=5120, z=1, resid, 160 blocks
  {
    GP g4 = {attn_b, wo_b, out_hidden, hs, 0.125f, NHEADS * VD, 20, 2048, HIDDEN, 2};
    gemm8p<<<dim3(160), 512, 0, stream>>>(g4, g4, 160, 20);
  }

  (void)in_sizes; (void)n_in; (void)out_size; (void)ws_size;
}

// Round 2
// 539.276 us; speedup vs baseline: 1.2081x; 1.2081x over previous
//
#include <hip/hip_runtime.h>
#include <hip/hip_bf16.h>

typedef __hip_bfloat16 bf16;
typedef __attribute__((ext_vector_type(8))) short bf16x8;
typedef __attribute__((ext_vector_type(4))) float f32x4;

#define S_LEN   2048
#define HIDDEN  5120
#define NHEADS  16
#define QLORA   1536
#define KVLORA  512
#define QKD     192
#define VD      128
#define QN      (NHEADS*QKD)          /* 3072 */
#define KVN     (NHEADS*(128+VD))     /* 4096 */
#define QCKN    2112                  /* 1536 qa | 512 ckv | 64 kpe */
#define SM_SCALE 0.07216878364870322f /* 192^-0.5 */

__device__ __forceinline__ f32x4 mfma16(bf16x8 a, bf16x8 b, f32x4 c) {
  return __builtin_amdgcn_mfma_f32_16x16x32_bf16(a, b, c, 0, 0, 0);
}
__device__ __forceinline__ void g2l16(const void* g, void* l) {
  __builtin_amdgcn_global_load_lds((const __attribute__((address_space(1))) void*)g,
                                   (__attribute__((address_space(3))) void*)l, 16, 0, 0);
}
__device__ __forceinline__ bf16x8 ld8(const bf16* p) { return *(const bf16x8*)p; }

// ---------------- fused fp32 -> bf16 cast over 5 weight segments ----------------
__global__ void cvt_multi(const float* s0, bf16* d0, int n0,
                          const float* s1, bf16* d1, int n1,
                          const float* s2, bf16* d2, int n2,
                          const float* s3, bf16* d3, int n3,
                          const float* s4, bf16* d4, int n4s)
{
  int i = blockIdx.x * 256 + threadIdx.x;
  const float* s; bf16* d;
  if (i < n0) { s = s0; d = d0; }
  else if ((i -= n0) < n1) { s = s1; d = d1; }
  else if ((i -= n1) < n2) { s = s2; d = d2; }
  else if ((i -= n2) < n3) { s = s3; d = d3; }
  else if ((i -= n3) < n4s) { s = s4; d = d4; }
  else return;
  const float4 v = ((const float4*)s)[i];
  union { bf16 b[4]; unsigned long long u; } pk;
  pk.b[0] = __float2bfloat16(v.x);
  pk.b[1] = __float2bfloat16(v.y);
  pk.b[2] = __float2bfloat16(v.z);
  pk.b[3] = __float2bfloat16(v.w);
  *(unsigned long long*)(d + (size_t)i * 4) = pk.u;
}

// ---------------- RMSNorm (fp32 in, bf16 out), one block per row ----------------
__global__ void rmsnorm_k(const float* __restrict__ in, int istride, int C,
                          const float* __restrict__ w,
                          bf16* __restrict__ out, int ostride)
{
  const int row = blockIdx.x;
  const float* x = in + (size_t)row * istride;
  float ss = 0.f;
  for (int c = threadIdx.x; c < C; c += 256) { float v = x[c]; ss += v * v; }
  #pragma unroll
  for (int m = 32; m >= 1; m >>= 1) ss += __shfl_xor(ss, m, 64);
  __shared__ float red[4];
  if ((threadIdx.x & 63) == 0) red[threadIdx.x >> 6] = ss;
  __syncthreads();
  ss = red[0] + red[1] + red[2] + red[3];
  const float sc = rsqrtf(ss / (float)C + 1e-6f);
  bf16* o = out + (size_t)row * ostride;
  for (int c = threadIdx.x; c < C; c += 256)
    o[c] = __float2bfloat16(x[c] * sc * w[c]);
}

// ---- fused dual RMSNorm over gemm1's 4 split-K PARTIALS (no atomics upstream):
// x = sum_z parts[z][row][c]. rows 0..S-1 -> qa (C=1536), rows S..2S-1 -> ckv
// (C=512). ckv blocks also emit the summed raw kpe cols (2048..2111) to a side
// buffer so the partials can be reused as scratch afterwards.
__global__ void rmsnorm2_k(const float* __restrict__ parts,  // [4][S][2112]
                           const float* __restrict__ wq, const float* __restrict__ wk,
                           bf16* __restrict__ qa_n, bf16* __restrict__ ckv_n,
                           float* __restrict__ kpe_sum)      // [S][64]
{
  const int r = blockIdx.x;
  const bool is_q = r < S_LEN;
  const int row = is_q ? r : r - S_LEN;
  const int C = is_q ? QLORA : KVLORA;
  const size_t PS = (size_t)S_LEN * QCKN;
  const float* x0 = parts + (size_t)row * QCKN + (is_q ? 0 : QLORA);
  const float* w = is_q ? wq : wk;
  bf16* o = (is_q ? qa_n + (size_t)row * QLORA : ckv_n + (size_t)row * KVLORA);
  __shared__ float xs[QLORA];
  float ss = 0.f;
  for (int c = threadIdx.x; c < C; c += 256) {
    const float v = x0[c] + x0[PS + c] + x0[2 * PS + c] + x0[3 * PS + c];
    xs[c] = v;
    ss += v * v;
  }
  #pragma unroll
  for (int m = 32; m >= 1; m >>= 1) ss += __shfl_xor(ss, m, 64);
  __shared__ float red[4];
  if ((threadIdx.x & 63) == 0) red[threadIdx.x >> 6] = ss;
  __syncthreads();
  ss = red[0] + red[1] + red[2] + red[3];
  const float sc = rsqrtf(ss / (float)C + 1e-6f);
  for (int c = threadIdx.x; c < C; c += 256)
    o[c] = __float2bfloat16(xs[c] * sc * w[c]);
  if (!is_q) {
    const float* kp = parts + (size_t)row * QCKN + 2048;
    for (int c = threadIdx.x; c < 64; c += 256)
      kpe_sum[row * 64 + c] = kp[c] + kp[PS + c] + kp[2 * PS + c] + kp[3 * PS + c];
  }
}

// ---------------- NT GEMM, BK=64: C[M,N] = A[M,K]*Bt[N,K]^T over K-chunk ----
// 128x128 tile, BK=64, 4 waves each 64x64, global_load_lds width 16. LDS 32 KB.
// launch_bounds(256,4): 4 blocks/CU co-resident (VGPR 56 + AGPR 64 = 120 <= 128
// cap) -> barrier vmcnt(0) drains hidden by other blocks' MFMA.
// SPLIT: split-K blocks write DISJOINT partial buffers C + z*M*N (plain
// stores); consumer kernels fuse the z-reduction. No atomics anywhere
// (r1 post-mortem: atomic RMW rate ~180G/s was a suspected wall; this
// also kills the RMW fetch and the zero-init pass).
template<bool RESID, bool CLAMPN, bool SPLIT>
__global__ __launch_bounds__(256, 4)
void gemm_nt(const bf16* __restrict__ A, const bf16* __restrict__ Bt,
             float* __restrict__ C, int M, int N, int lda, int klen,
             const float* __restrict__ resid, float rscale)
{
  __shared__ bf16 As[2 * 128 * 32];   // chunk-major: [c][row][32]
  __shared__ bf16 Bs[2 * 128 * 32];
  const int tid = threadIdx.x;
  const int wave = tid >> 6;
  const int lane = tid & 63;
  const int l15 = lane & 15, quad = lane >> 4;
  const int bm = blockIdx.x * 128, bn = blockIdx.y * 128;
  const int kbase = blockIdx.z * klen;
  const int wm = (wave >> 1) * 64, wn = (wave & 1) * 64;

  const int srow = tid >> 2;        // 0..63
  const int scol = (tid & 3) * 8;   // 0,8,16,24
  const bf16* Ag0 = A + (size_t)(bm + srow) * lda + kbase + scol;
  const bf16* Ag1 = A + (size_t)(bm + 64 + srow) * lda + kbase + scol;
  int bn0 = bn + srow, bn1 = bn + 64 + srow;
  if (CLAMPN) { bn0 = min(bn0, N - 1); bn1 = min(bn1, N - 1); }
  const bf16* Bg0 = Bt + (size_t)bn0 * lda + kbase + scol;
  const bf16* Bg1 = Bt + (size_t)bn1 * lda + kbase + scol;

  char* AsW = (char*)As + wave * 1024;
  char* BsW = (char*)Bs + wave * 1024;

  f32x4 acc[4][4];
  #pragma unroll
  for (int i = 0; i < 4; i++)
    #pragma unroll
    for (int j = 0; j < 4; j++) acc[i][j] = (f32x4){0.f, 0.f, 0.f, 0.f};

  const int nk = klen >> 6;
  for (int kt = 0; kt < nk; ++kt) {
    const int k0 = kt << 6;
    #pragma unroll
    for (int c = 0; c < 2; ++c) {
      g2l16(Ag0 + k0 + c * 32, AsW + c * 8192);
      g2l16(Ag1 + k0 + c * 32, AsW + c * 8192 + 4096);
      g2l16(Bg0 + k0 + c * 32, BsW + c * 8192);
      g2l16(Bg1 + k0 + c * 32, BsW + c * 8192 + 4096);
    }
    __syncthreads();
    #pragma unroll
    for (int c = 0; c < 2; ++c) {
      bf16x8 af[4], bfr[4];
      #pragma unroll
      for (int i = 0; i < 4; i++)
        af[i] = ld8(As + c * 4096 + (wm + i * 16 + l15) * 32 + quad * 8);
      #pragma unroll
      for (int j = 0; j < 4; j++)
        bfr[j] = ld8(Bs + c * 4096 + (wn + j * 16 + l15) * 32 + quad * 8);
      #pragma unroll
      for (int i = 0; i < 4; i++)
        #pragma unroll
        for (int j = 0; j < 4; j++)
          acc[i][j] = mfma16(af[i], bfr[j], acc[i][j]);
    }
    __syncthreads();
  }

  float* Cb = C;
  if (SPLIT) Cb += (size_t)blockIdx.z * ((size_t)S_LEN * (size_t)N);
  #pragma unroll
  for (int i = 0; i < 4; i++)
    #pragma unroll
    for (int j = 0; j < 4; j++) {
      const int row = bm + wm + i * 16 + quad * 4;
      const int col = bn + wn + j * 16 + l15;
      if (!CLAMPN || col < N) {
        #pragma unroll
        for (int r = 0; r < 4; r++) {
          float v = acc[i][j][r];
          const size_t idx = (size_t)(row + r) * N + col;
          if (RESID) v += resid[idx] * rscale;
          Cb[idx] = v;
        }
      }
    }
}

// ---------------- RoPE + assemble q/k (bf16 for attn, fp32 k out) ----------------
// q comes as 2 split-K partials [2][S][3072]; summed here (fused reduction).
__global__ void rope_assemble_k(
    const float* __restrict__ qp,      // [2][S, 3072]
    const float* __restrict__ kpe_sum, // [S, 64]
    const float* __restrict__ kv,      // [S, 4096]
    const int*   __restrict__ pos,     // [S]
    float* __restrict__ k_out,         // [16,S,192]
    bf16*  __restrict__ q_bf,          // [16,S,192]
    bf16*  __restrict__ k_bf)          // [16,S,192]
{
  const int s = blockIdx.x;
  const int t = threadIdx.x;
  const size_t QPS = (size_t)S_LEN * QN;
  __shared__ float cs[32], sn[32], kpe[64];
  const float p = (float)pos[s];
  if (t < 32) {
    const float inv = powf(10000.0f, -((float)(2 * t)) / 64.0f);
    const float f = p * inv;
    float si, c;
    sincosf(f, &si, &c);
    cs[t] = c; sn[t] = si;
    const float r0v = kpe_sum[(size_t)s * 64 + 2 * t];
    const float r1v = kpe_sum[(size_t)s * 64 + 2 * t + 1];
    kpe[t]      = r0v * c - r1v * si;
    kpe[32 + t] = r1v * c + r0v * si;
  }
  __syncthreads();
  for (int i = t; i < NHEADS * 128; i += 256) {
    const int h = i >> 7, d = i & 127;
    const size_t o = ((size_t)h * S_LEN + s) * QKD + d;
    const float kn = kv[(size_t)s * KVN + h * 256 + d];
    k_out[o] = kn;
    k_bf[o] = __float2bfloat16(kn);
    const size_t qi = (size_t)s * QN + h * QKD + d;
    q_bf[o] = __float2bfloat16(qp[qi] + qp[QPS + qi]);
  }
  for (int i = t; i < NHEADS * 32; i += 256) {
    const int h = i >> 5, jj = i & 31;
    const size_t qi = (size_t)s * QN + h * QKD + 128 + 2 * jj;
    const float r0v = qp[qi] + qp[QPS + qi];
    const float r1v = qp[qi + 1] + qp[QPS + qi + 1];
    const float c = cs[jj], si = sn[jj];
    const size_t o = ((size_t)h * S_LEN + s) * QKD + 128;
    q_bf[o + jj]      = __float2bfloat16(r0v * c - r1v * si);
    q_bf[o + 32 + jj] = __float2bfloat16(r1v * c + r0v * si);
  }
  for (int i = t; i < NHEADS * 64; i += 256) {
    const int h = i >> 6, jj = i & 63;
    const float v = kpe[jj];
    const size_t o = ((size_t)h * S_LEN + s) * QKD + 128 + jj;
    k_out[o] = v;
    k_bf[o] = __float2bfloat16(v);
  }
}

// ---------------- V: fp32 out + bf16 transpose [16][128][2048] ----------------
__global__ void v_transpose_k(const float* __restrict__ kv,
                              float* __restrict__ v_out,
                              bf16* __restrict__ vt_bf)
{
  const int h = blockIdx.x, st = blockIdx.y, dt = blockIdx.z;
  __shared__ float tile[32][33];
  const int tx = threadIdx.x & 31;
  const int ty = (threadIdx.x >> 5) * 4;
  const int s0 = st * 32, d0 = dt * 32;
  #pragma unroll
  for (int r = 0; r < 4; r++) {
    const int sl = ty + r;
    const float v = kv[(size_t)(s0 + sl) * KVN + h * 256 + 128 + d0 + tx];
    v_out[((size_t)h * S_LEN + s0 + sl) * VD + d0 + tx] = v;
    tile[sl][tx] = v;
  }
  __syncthreads();
  #pragma unroll
  for (int r = 0; r < 4; r++) {
    const int dl = ty + r;
    vt_bf[((size_t)h * VD + d0 + dl) * S_LEN + s0 + tx] = __float2bfloat16(tile[tx][dl]);
  }
}

// ---------------- causal flash attention (v4, unchanged) ----------------
__global__ __launch_bounds__(256, 3)
void attn_k(const bf16* __restrict__ qb, const bf16* __restrict__ kb,
            const bf16* __restrict__ vt, bf16* __restrict__ aout)
{
  const int head = blockIdx.y;
  const int qt = (head < 8) ? blockIdx.x : (gridDim.x - 1 - blockIdx.x);
  const int wave = threadIdx.x >> 6, lane = threadIdx.x & 63;
  const int l15 = lane & 15, quad = lane >> 4;
  const int r0 = qt * 64 + wave * 16;

  const bf16* qh = qb + (size_t)head * S_LEN * QKD;
  const bf16* kh = kb + (size_t)head * S_LEN * QKD;
  const bf16* vh = vt + (size_t)head * VD * S_LEN;

  __shared__ bf16 Ks[6 * 64 * 32];
  __shared__ bf16 Vs[128 * 72];
  __shared__ bf16 Plds[4][16][72];

  const int tid = threadIdx.x;
  const int srow = wave * 16 + (lane >> 2);
  const int scol = (lane & 3) * 8;
  const bf16* ksrc = kh + (size_t)srow * QKD + scol;
  bf16* kdst = Ks + srow * 32 + scol;
  const int vrow = tid >> 1;
  const int vcol = (tid & 1) * 32;
  const bf16* vsrc = vh + (size_t)vrow * S_LEN + vcol;
  bf16* vdst = Vs + vrow * 72 + vcol;

  bf16x8 qf[6];
  #pragma unroll
  for (int c = 0; c < 6; ++c)
    qf[c] = ld8(qh + (size_t)(r0 + l15) * QKD + c * 32 + quad * 8);

  f32x4 O[8];
  #pragma unroll
  for (int d = 0; d < 8; ++d) O[d] = (f32x4){0.f, 0.f, 0.f, 0.f};
  float mrow[4] = {-1e30f, -1e30f, -1e30f, -1e30f};
  float lrow[4] = {0.f, 0.f, 0.f, 0.f};

  bf16x8 kreg[6], vreg[4];
  #pragma unroll
  for (int c = 0; c < 6; ++c) kreg[c] = ld8(ksrc + c * 32);
  #pragma unroll
  for (int c = 0; c < 4; ++c) vreg[c] = ld8(vsrc + c * 8);

  for (int j = 0; j <= qt; ++j) {
    __syncthreads();
    #pragma unroll
    for (int c = 0; c < 6; ++c) *(bf16x8*)(kdst + c * 2048) = kreg[c];
    #pragma unroll
    for (int c = 0; c < 4; ++c) *(bf16x8*)(vdst + c * 8) = vreg[c];
    __syncthreads();
    if (j < qt) {
      const bf16* src = ksrc + (size_t)(j + 1) * 64 * QKD;
      #pragma unroll
      for (int c = 0; c < 6; ++c) kreg[c] = ld8(src + c * 32);
      const bf16* vs2 = vsrc + (size_t)(j + 1) * 64;
      #pragma unroll
      for (int c = 0; c < 4; ++c) vreg[c] = ld8(vs2 + c * 8);
    }
    const int kc = j * 64;

    f32x4 S[4];
    #pragma unroll
    for (int nt = 0; nt < 4; ++nt) S[nt] = (f32x4){0.f, 0.f, 0.f, 0.f};
    #pragma unroll
    for (int c = 0; c < 6; ++c) {
      #pragma unroll
      for (int nt = 0; nt < 4; ++nt) {
        const bf16x8 kf = ld8(Ks + c * 2048 + (nt * 16 + l15) * 32 + quad * 8);
        S[nt] = mfma16(qf[c], kf, S[nt]);
      }
    }

    float mnew[4] = {-1e30f, -1e30f, -1e30f, -1e30f};
    if (j == qt) {
      #pragma unroll
      for (int nt = 0; nt < 4; ++nt) {
        const int col = kc + nt * 16 + l15;
        #pragma unroll
        for (int r = 0; r < 4; r++) {
          const int row = r0 + quad * 4 + r;
          const float v = (col <= row) ? S[nt][r] * SM_SCALE : -1e30f;
          S[nt][r] = v;
          mnew[r] = fmaxf(mnew[r], v);
        }
      }
    } else {
      #pragma unroll
      for (int nt = 0; nt < 4; ++nt)
        #pragma unroll
        for (int r = 0; r < 4; r++) {
          const float v = S[nt][r] * SM_SCALE;
          S[nt][r] = v;
          mnew[r] = fmaxf(mnew[r], v);
        }
    }
    #pragma unroll
    for (int m = 8; m >= 1; m >>= 1)
      #pragma unroll
      for (int r = 0; r < 4; r++)
        mnew[r] = fmaxf(mnew[r], __shfl_xor(mnew[r], m, 64));
    float alpha[4], ladd[4] = {0.f, 0.f, 0.f, 0.f};
    #pragma unroll
    for (int r = 0; r < 4; r++) {
      const float mi = fmaxf(mrow[r], mnew[r]);
      alpha[r] = __expf(mrow[r] - mi);
      mrow[r] = mi;
    }
    #pragma unroll
    for (int nt = 0; nt < 4; ++nt)
      #pragma unroll
      for (int r = 0; r < 4; r++) {
        const float pv = __expf(S[nt][r] - mrow[r]);
        S[nt][r] = pv;
        ladd[r] += pv;
      }
    #pragma unroll
    for (int m = 8; m >= 1; m >>= 1)
      #pragma unroll
      for (int r = 0; r < 4; r++) ladd[r] += __shfl_xor(ladd[r], m, 64);
    #pragma unroll
    for (int r = 0; r < 4; r++) lrow[r] = lrow[r] * alpha[r] + ladd[r];
    #pragma unroll
    for (int d = 0; d < 8; ++d)
      #pragma unroll
      for (int r = 0; r < 4; r++) O[d][r] *= alpha[r];

    #pragma unroll
    for (int nt = 0; nt < 4; ++nt)
      #pragma unroll
      for (int r = 0; r < 4; r++)
        Plds[wave][quad * 4 + r][nt * 16 + l15] = __float2bfloat16(S[nt][r]);

    #pragma unroll
    for (int kt = 0; kt < 2; ++kt) {
      const bf16x8 pf = ld8(&Plds[wave][l15][kt * 32 + quad * 8]);
      #pragma unroll
      for (int dt = 0; dt < 8; ++dt) {
        const bf16x8 vf = ld8(Vs + (dt * 16 + l15) * 72 + kt * 32 + quad * 8);
        O[dt] = mfma16(pf, vf, O[dt]);
      }
    }
  }

  #pragma unroll
  for (int dt = 0; dt < 8; ++dt) {
    const int col = head * VD + dt * 16 + l15;
    #pragma unroll
    for (int r = 0; r < 4; r++) {
      const int row = r0 + quad * 4 + r;
      aout[(size_t)row * (NHEADS * VD) + col] = __float2bfloat16(O[dt][r] / lrow[r]);
    }
  }
}

// ---------------- host orchestration ----------------
extern "C" void kernel_launch(void* const* d_in, const int* in_sizes, int n_in,
                              void* d_out, int out_size, void* d_ws, size_t ws_size,
                              hipStream_t stream)
{
  const float* hs      = (const float*)d_in[0];
  const int*   pos     = (const int*)  d_in[1];
  const float* ln_w    = (const float*)d_in[3];
  const float* wq_a    = (const float*)d_in[4];
  const float* q_a_ln  = (const float*)d_in[5];
  const float* wq_b    = (const float*)d_in[6];
  const float* wkv_a   = (const float*)d_in[7];
  const float* kv_a_ln = (const float*)d_in[8];
  const float* wkv_b   = (const float*)d_in[9];
  const float* wo      = (const float*)d_in[10];

  float* out_hidden = (float*)d_out;
  float* out_k = out_hidden + (size_t)S_LEN * HIDDEN;
  float* out_v = out_k + (size_t)NHEADS * S_LEN * QKD;

  char* ws = (char*)d_ws;
  size_t off = 0;
  auto alloc = [&](size_t bytes) { char* p = ws + off; off += (bytes + 255) & ~255ULL; return p; };

  bf16* h_b     = (bf16*)alloc((size_t)S_LEN * HIDDEN * 2);
  bf16* w1_b    = (bf16*)alloc((size_t)QCKN * HIDDEN * 2);
  bf16* wqb_b   = (bf16*)alloc((size_t)QN * QLORA * 2);
  bf16* wkvb_b  = (bf16*)alloc((size_t)KVN * KVLORA * 2);
  bf16* wo_b    = (bf16*)alloc((size_t)HIDDEN * (NHEADS * VD) * 2);
  // scratch region reused twice:
  //   phase 1: gemm1 partials [4][S][2112] fp32            (69.2 MB)
  //   phase 2: q partials [2][S][3072] fp32 + kv_f [S][4096] fp32 (83.9 MB)
  char* region  = alloc((size_t)2 * S_LEN * QN * 4 + (size_t)S_LEN * KVN * 4);
  float* qa_parts = (float*)region;
  float* q_f      = (float*)region;                       // alias (after rmsnorm2)
  float* kv_f     = (float*)(region + (size_t)2 * S_LEN * QN * 4);
  float* kpe_sum = (float*)alloc((size_t)S_LEN * 64 * 4);
  bf16* qa_n    = (bf16*)alloc((size_t)S_LEN * QLORA * 2);
  bf16* ckv_n   = (bf16*)alloc((size_t)S_LEN * KVLORA * 2);
  bf16* q_bf    = (bf16*)alloc((size_t)NHEADS * S_LEN * QKD * 2);
  bf16* k_bf    = (bf16*)alloc((size_t)NHEADS * S_LEN * QKD * 2);
  bf16* vt_bf   = (bf16*)alloc((size_t)NHEADS * VD * S_LEN * 2);
  bf16* attn_b  = (bf16*)alloc((size_t)S_LEN * (NHEADS * VD) * 2);

  {
    const int n0 = (QLORA * HIDDEN) / 4;
    const int n1 = ((QCKN - QLORA) * HIDDEN) / 4;
    const int n2 = (QN * QLORA) / 4;
    const int n3 = (KVN * KVLORA) / 4;
    const int n4s = (HIDDEN * NHEADS * VD) / 4;
    const int tot = n0 + n1 + n2 + n3 + n4s;
    cvt_multi<<<(tot + 255) / 256, 256, 0, stream>>>(
        wq_a, w1_b, n0,
        wkv_a, w1_b + (size_t)QLORA * HIDDEN, n1,
        wq_b, wqb_b, n2,
        wkv_b, wkvb_b, n3,
        wo, wo_b, n4s);
  }

  rmsnorm_k<<<S_LEN, 256, 0, stream>>>(hs, HIDDEN, HIDDEN, ln_w, h_b, HIDDEN);

  // gemm1: [qa|ckv|kpe] partials = h @ w1^T  (split-K x4 -> 1088 blocks,
  // klen=1280, disjoint partial outputs, plain stores)
  gemm_nt<false, true, true><<<dim3(16, 17, 4), 256, 0, stream>>>(
      h_b, w1_b, qa_parts, S_LEN, QCKN, HIDDEN, HIDDEN / 4, nullptr, 0.f);

  // fused dual rmsnorm + 4-way partial reduction + kpe extraction
  rmsnorm2_k<<<2 * S_LEN, 256, 0, stream>>>(qa_parts, q_a_ln, kv_a_ln,
                                            qa_n, ckv_n, kpe_sum);

  // q partials = qa_n @ wq_b^T (split-K x2 -> 768 blocks, klen=768; reduction
  // fused into rope_assemble). Overwrites qa_parts region (dead now).
  gemm_nt<false, false, true><<<dim3(16, QN / 128, 2), 256, 0, stream>>>(
      qa_n, wqb_b, q_f, S_LEN, QN, QLORA, QLORA / 2, nullptr, 0.f);
  // kv = ckv_n @ wkv_b^T  (512 blocks, klen=512, plain store)
  gemm_nt<false, false, false><<<dim3(16, KVN / 128, 1), 256, 0, stream>>>(
      ckv_n, wkvb_b, kv_f, S_LEN, KVN, KVLORA, KVLORA, nullptr, 0.f);

  rope_assemble_k<<<S_LEN, 256, 0, stream>>>(q_f, kpe_sum, kv_f, pos,
                                             out_k, q_bf, k_bf);
  v_transpose_k<<<dim3(NHEADS, S_LEN / 32, VD / 32), 256, 0, stream>>>(kv_f, out_v, vt_bf);

  attn_k<<<dim3(S_LEN / 64, NHEADS), 256, 0, stream>>>(q_bf, k_bf, vt_bf, attn_b);

  // gemm4: out = attn @ wo^T + hs*0.125  (640 blocks, klen=2048, plain store)
  gemm_nt<true, false, false><<<dim3(16, HIDDEN / 128, 1), 256, 0, stream>>>(
      attn_b, wo_b, out_hidden, S_LEN, HIDDEN, NHEADS * VD, NHEADS * VD, hs, 0.125f);

  (void)in_sizes; (void)n_in; (void)out_size; (void)ws_size;
}

// Round 3
// 539.068 us; speedup vs baseline: 1.2086x; 1.0004x over previous
//
#include <hip/hip_runtime.h>
#include <hip/hip_bf16.h>

typedef __hip_bfloat16 bf16;
typedef __attribute__((ext_vector_type(8))) short bf16x8;
typedef __attribute__((ext_vector_type(4))) float f32x4;

#define S_LEN   2048
#define HIDDEN  5120
#define NHEADS  16
#define QLORA   1536
#define KVLORA  512
#define QKD     192
#define VD      128
#define QN      (NHEADS*QKD)          /* 3072 */
#define KVN     (NHEADS*(128+VD))     /* 4096 */
#define QCKN    2112                  /* 1536 qa | 512 ckv | 64 kpe */
#define SM_SCALE 0.07216878364870322f /* 192^-0.5 */

__device__ __forceinline__ f32x4 mfma16(bf16x8 a, bf16x8 b, f32x4 c) {
  return __builtin_amdgcn_mfma_f32_16x16x32_bf16(a, b, c, 0, 0, 0);
}
__device__ __forceinline__ void g2l16(const void* g, void* l) {
  __builtin_amdgcn_global_load_lds((const __attribute__((address_space(1))) void*)g,
                                   (__attribute__((address_space(3))) void*)l, 16, 0, 0);
}
__device__ __forceinline__ bf16x8 ld8(const bf16* p) { return *(const bf16x8*)p; }

// ---------------- fused fp32 -> bf16 cast over 5 weight segments ----------------
__global__ void cvt_multi(const float* s0, bf16* d0, int n0,
                          const float* s1, bf16* d1, int n1,
                          const float* s2, bf16* d2, int n2,
                          const float* s3, bf16* d3, int n3,
                          const float* s4, bf16* d4, int n4s)
{
  int i = blockIdx.x * 256 + threadIdx.x;
  const float* s; bf16* d;
  if (i < n0) { s = s0; d = d0; }
  else if ((i -= n0) < n1) { s = s1; d = d1; }
  else if ((i -= n1) < n2) { s = s2; d = d2; }
  else if ((i -= n2) < n3) { s = s3; d = d3; }
  else if ((i -= n3) < n4s) { s = s4; d = d4; }
  else return;
  const float4 v = ((const float4*)s)[i];
  union { bf16 b[4]; unsigned long long u; } pk;
  pk.b[0] = __float2bfloat16(v.x);
  pk.b[1] = __float2bfloat16(v.y);
  pk.b[2] = __float2bfloat16(v.z);
  pk.b[3] = __float2bfloat16(v.w);
  *(unsigned long long*)(d + (size_t)i * 4) = pk.u;
}

// ---------------- RMSNorm (fp32 in, bf16 out), one block per row ----------------
__global__ void rmsnorm_k(const float* __restrict__ in, int istride, int C,
                          const float* __restrict__ w,
                          bf16* __restrict__ out, int ostride)
{
  const int row = blockIdx.x;
  const float* x = in + (size_t)row * istride;
  float ss = 0.f;
  for (int c = threadIdx.x; c < C; c += 256) { float v = x[c]; ss += v * v; }
  #pragma unroll
  for (int m = 32; m >= 1; m >>= 1) ss += __shfl_xor(ss, m, 64);
  __shared__ float red[4];
  if ((threadIdx.x & 63) == 0) red[threadIdx.x >> 6] = ss;
  __syncthreads();
  ss = red[0] + red[1] + red[2] + red[3];
  const float sc = rsqrtf(ss / (float)C + 1e-6f);
  bf16* o = out + (size_t)row * ostride;
  for (int c = threadIdx.x; c < C; c += 256)
    o[c] = __float2bfloat16(x[c] * sc * w[c]);
}

// ---- fused dual RMSNorm over gemm1's 4 split-K PARTIALS (no atomics upstream):
__global__ void rmsnorm2_k(const float* __restrict__ parts,  // [4][S][2112]
                           const float* __restrict__ wq, const float* __restrict__ wk,
                           bf16* __restrict__ qa_n, bf16* __restrict__ ckv_n,
                           float* __restrict__ kpe_sum)      // [S][64]
{
  const int r = blockIdx.x;
  const bool is_q = r < S_LEN;
  const int row = is_q ? r : r - S_LEN;
  const int C = is_q ? QLORA : KVLORA;
  const size_t PS = (size_t)S_LEN * QCKN;
  const float* x0 = parts + (size_t)row * QCKN + (is_q ? 0 : QLORA);
  const float* w = is_q ? wq : wk;
  bf16* o = (is_q ? qa_n + (size_t)row * QLORA : ckv_n + (size_t)row * KVLORA);
  __shared__ float xs[QLORA];
  float ss = 0.f;
  for (int c = threadIdx.x; c < C; c += 256) {
    const float v = x0[c] + x0[PS + c] + x0[2 * PS + c] + x0[3 * PS + c];
    xs[c] = v;
    ss += v * v;
  }
  #pragma unroll
  for (int m = 32; m >= 1; m >>= 1) ss += __shfl_xor(ss, m, 64);
  __shared__ float red[4];
  if ((threadIdx.x & 63) == 0) red[threadIdx.x >> 6] = ss;
  __syncthreads();
  ss = red[0] + red[1] + red[2] + red[3];
  const float sc = rsqrtf(ss / (float)C + 1e-6f);
  for (int c = threadIdx.x; c < C; c += 256)
    o[c] = __float2bfloat16(xs[c] * sc * w[c]);
  if (!is_q) {
    const float* kp = parts + (size_t)row * QCKN + 2048;
    for (int c = threadIdx.x; c < 64; c += 256)
      kpe_sum[row * 64 + c] = kp[c] + kp[PS + c] + kp[2 * PS + c] + kp[3 * PS + c];
  }
}

// ---------------- NT GEMM, BK=64: C[M,N] = A[M,K]*Bt[N,K]^T over K-chunk ----
// 128x128 tile, BK=64, 4 waves each 64x64, global_load_lds width 16. LDS 32 KB.
// T2 swizzle (rule 21): LDS dest linear, global SOURCE col pre-swizzled with
// col8 ^= (row>>1)&3, ds_read col applies the same XOR -> 8-way read conflict
// becomes 2-way (free). Regime-gate test: guide predicts ~null at 2-phase.
template<bool RESID, bool CLAMPN, bool SPLIT>
__global__ __launch_bounds__(256, 4)
void gemm_nt(const bf16* __restrict__ A, const bf16* __restrict__ Bt,
             float* __restrict__ C, int M, int N, int lda, int klen,
             const float* __restrict__ resid, float rscale)
{
  __shared__ bf16 As[2 * 128 * 32];   // chunk-major: [c][row][32]
  __shared__ bf16 Bs[2 * 128 * 32];
  const int tid = threadIdx.x;
  const int wave = tid >> 6;
  const int lane = tid & 63;
  const int l15 = lane & 15, quad = lane >> 4;
  const int bm = blockIdx.x * 128, bn = blockIdx.y * 128;
  const int kbase = blockIdx.z * klen;
  const int wm = (wave >> 1) * 64, wn = (wave & 1) * 64;

  const int srow = tid >> 2;        // 0..63
  // pre-swizzled source col: (tid>>3)&3 == (row>>1)&3 for row=srow (and +64)
  const int scol = (((tid & 3) ^ ((tid >> 3) & 3)) << 3);
  const bf16* Ag0 = A + (size_t)(bm + srow) * lda + kbase + scol;
  const bf16* Ag1 = A + (size_t)(bm + 64 + srow) * lda + kbase + scol;
  int bn0 = bn + srow, bn1 = bn + 64 + srow;
  if (CLAMPN) { bn0 = min(bn0, N - 1); bn1 = min(bn1, N - 1); }
  const bf16* Bg0 = Bt + (size_t)bn0 * lda + kbase + scol;
  const bf16* Bg1 = Bt + (size_t)bn1 * lda + kbase + scol;

  char* AsW = (char*)As + wave * 1024;
  char* BsW = (char*)Bs + wave * 1024;

  // swizzled frag-read col: (row>>1)&3 == (l15>>1)&3 (wm, i*16 are 0 mod 4 after >>1)
  const int qs = ((quad ^ ((l15 >> 1) & 3)) << 3);

  f32x4 acc[4][4];
  #pragma unroll
  for (int i = 0; i < 4; i++)
    #pragma unroll
    for (int j = 0; j < 4; j++) acc[i][j] = (f32x4){0.f, 0.f, 0.f, 0.f};

  const int nk = klen >> 6;
  for (int kt = 0; kt < nk; ++kt) {
    const int k0 = kt << 6;
    #pragma unroll
    for (int c = 0; c < 2; ++c) {
      g2l16(Ag0 + k0 + c * 32, AsW + c * 8192);
      g2l16(Ag1 + k0 + c * 32, AsW + c * 8192 + 4096);
      g2l16(Bg0 + k0 + c * 32, BsW + c * 8192);
      g2l16(Bg1 + k0 + c * 32, BsW + c * 8192 + 4096);
    }
    __syncthreads();
    #pragma unroll
    for (int c = 0; c < 2; ++c) {
      bf16x8 af[4], bfr[4];
      #pragma unroll
      for (int i = 0; i < 4; i++)
        af[i] = ld8(As + c * 4096 + (wm + i * 16 + l15) * 32 + qs);
      #pragma unroll
      for (int j = 0; j < 4; j++)
        bfr[j] = ld8(Bs + c * 4096 + (wn + j * 16 + l15) * 32 + qs);
      #pragma unroll
      for (int i = 0; i < 4; i++)
        #pragma unroll
        for (int j = 0; j < 4; j++)
          acc[i][j] = mfma16(af[i], bfr[j], acc[i][j]);
    }
    __syncthreads();
  }

  float* Cb = C;
  if (SPLIT) Cb += (size_t)blockIdx.z * ((size_t)S_LEN * (size_t)N);
  #pragma unroll
  for (int i = 0; i < 4; i++)
    #pragma unroll
    for (int j = 0; j < 4; j++) {
      const int row = bm + wm + i * 16 + quad * 4;
      const int col = bn + wn + j * 16 + l15;
      if (!CLAMPN || col < N) {
        #pragma unroll
        for (int r = 0; r < 4; r++) {
          float v = acc[i][j][r];
          const size_t idx = (size_t)(row + r) * N + col;
          if (RESID) v += resid[idx] * rscale;
          Cb[idx] = v;
        }
      }
    }
}

// ---------------- RoPE + assemble q/k (bf16 for attn, fp32 k out) ----------------
// q comes as 2 split-K partials [2][S][3072]; summed here (fused reduction).
__global__ void rope_assemble_k(
    const float* __restrict__ qp,      // [2][S, 3072]
    const float* __restrict__ kpe_sum, // [S, 64]
    const float* __restrict__ kv,      // [S, 4096]
    const int*   __restrict__ pos,     // [S]
    float* __restrict__ k_out,         // [16,S,192]
    bf16*  __restrict__ q_bf,          // [16,S,192]
    bf16*  __restrict__ k_bf)          // [16,S,192]
{
  const int s = blockIdx.x;
  const int t = threadIdx.x;
  const size_t QPS = (size_t)S_LEN * QN;
  __shared__ float cs[32], sn[32], kpe[64];
  const float p = (float)pos[s];
  if (t < 32) {
    const float inv = powf(10000.0f, -((float)(2 * t)) / 64.0f);
    const float f = p * inv;
    float si, c;
    sincosf(f, &si, &c);
    cs[t] = c; sn[t] = si;
    const float r0v = kpe_sum[(size_t)s * 64 + 2 * t];
    const float r1v = kpe_sum[(size_t)s * 64 + 2 * t + 1];
    kpe[t]      = r0v * c - r1v * si;
    kpe[32 + t] = r1v * c + r0v * si;
  }
  __syncthreads();
  for (int i = t; i < NHEADS * 128; i += 256) {
    const int h = i >> 7, d = i & 127;
    const size_t o = ((size_t)h * S_LEN + s) * QKD + d;
    const float kn = kv[(size_t)s * KVN + h * 256 + d];
    k_out[o] = kn;
    k_bf[o] = __float2bfloat16(kn);
    const size_t qi = (size_t)s * QN + h * QKD + d;
    q_bf[o] = __float2bfloat16(qp[qi] + qp[QPS + qi]);
  }
  for (int i = t; i < NHEADS * 32; i += 256) {
    const int h = i >> 5, jj = i & 31;
    const size_t qi = (size_t)s * QN + h * QKD + 128 + 2 * jj;
    const float r0v = qp[qi] + qp[QPS + qi];
    const float r1v = qp[qi + 1] + qp[QPS + qi + 1];
    const float c = cs[jj], si = sn[jj];
    const size_t o = ((size_t)h * S_LEN + s) * QKD + 128;
    q_bf[o + jj]      = __float2bfloat16(r0v * c - r1v * si);
    q_bf[o + 32 + jj] = __float2bfloat16(r1v * c + r0v * si);
  }
  for (int i = t; i < NHEADS * 64; i += 256) {
    const int h = i >> 6, jj = i & 63;
    const float v = kpe[jj];
    const size_t o = ((size_t)h * S_LEN + s) * QKD + 128 + jj;
    k_out[o] = v;
    k_bf[o] = __float2bfloat16(v);
  }
}

// ---------------- V: fp32 out + bf16 transpose [16][128][2048] ----------------
__global__ void v_transpose_k(const float* __restrict__ kv,
                              float* __restrict__ v_out,
                              bf16* __restrict__ vt_bf)
{
  const int h = blockIdx.x, st = blockIdx.y, dt = blockIdx.z;
  __shared__ float tile[32][33];
  const int tx = threadIdx.x & 31;
  const int ty = (threadIdx.x >> 5) * 4;
  const int s0 = st * 32, d0 = dt * 32;
  #pragma unroll
  for (int r = 0; r < 4; r++) {
    const int sl = ty + r;
    const float v = kv[(size_t)(s0 + sl) * KVN + h * 256 + 128 + d0 + tx];
    v_out[((size_t)h * S_LEN + s0 + sl) * VD + d0 + tx] = v;
    tile[sl][tx] = v;
  }
  __syncthreads();
  #pragma unroll
  for (int r = 0; r < 4; r++) {
    const int dl = ty + r;
    vt_bf[((size_t)h * VD + d0 + dl) * S_LEN + s0 + tx] = __float2bfloat16(tile[tx][dl]);
  }
}

// ---------------- causal flash attention ----------------
// r3 changes: (a) Ks XOR-swizzle col8 ^= (row>>1)&3 on write+read -> 8-way
// QK^T frag-read conflict becomes 2-way; (b) XCD-aware remap: linear block id
// -> xcd = id&7 owns heads {2c, 2c+1}, so each XCD's L2 keeps only its own
// ~3 MB of K/V (was: every XCD fetched every head).
__global__ __launch_bounds__(256, 3)
void attn_k(const bf16* __restrict__ qb, const bf16* __restrict__ kb,
            const bf16* __restrict__ vt, bf16* __restrict__ aout)
{
  const int lin = blockIdx.x + blockIdx.y * 32;   // gridDim = (32, 16)
  const int xcd = lin & 7;
  const int idx = lin >> 3;                       // 0..63
  const int head = xcd * 2 + (idx >> 5);
  const int qt = (idx >> 5) ? (31 - (idx & 31)) : (idx & 31);
  const int wave = threadIdx.x >> 6, lane = threadIdx.x & 63;
  const int l15 = lane & 15, quad = lane >> 4;
  const int r0 = qt * 64 + wave * 16;

  const bf16* qh = qb + (size_t)head * S_LEN * QKD;
  const bf16* kh = kb + (size_t)head * S_LEN * QKD;
  const bf16* vh = vt + (size_t)head * VD * S_LEN;

  __shared__ bf16 Ks[6 * 64 * 32];
  __shared__ bf16 Vs[128 * 72];
  __shared__ bf16 Plds[4][16][72];

  const int tid = threadIdx.x;
  const int srow = wave * 16 + (lane >> 2);
  const int scol = (lane & 3) * 8;
  const bf16* ksrc = kh + (size_t)srow * QKD + scol;
  // swizzled LDS write col (srow>>1)&3 == (lane>>3)&3 (wave*16 is 0 mod 4 after >>1)
  bf16* kdst = Ks + srow * 32 + (((lane & 3) ^ ((lane >> 3) & 3)) << 3);
  const int vrow = tid >> 1;
  const int vcol = (tid & 1) * 32;
  const bf16* vsrc = vh + (size_t)vrow * S_LEN + vcol;
  bf16* vdst = Vs + vrow * 72 + vcol;

  // swizzled Ks frag-read col
  const int qs = ((quad ^ ((l15 >> 1) & 3)) << 3);

  bf16x8 qf[6];
  #pragma unroll
  for (int c = 0; c < 6; ++c)
    qf[c] = ld8(qh + (size_t)(r0 + l15) * QKD + c * 32 + quad * 8);

  f32x4 O[8];
  #pragma unroll
  for (int d = 0; d < 8; ++d) O[d] = (f32x4){0.f, 0.f, 0.f, 0.f};
  float mrow[4] = {-1e30f, -1e30f, -1e30f, -1e30f};
  float lrow[4] = {0.f, 0.f, 0.f, 0.f};

  bf16x8 kreg[6], vreg[4];
  #pragma unroll
  for (int c = 0; c < 6; ++c) kreg[c] = ld8(ksrc + c * 32);
  #pragma unroll
  for (int c = 0; c < 4; ++c) vreg[c] = ld8(vsrc + c * 8);

  for (int j = 0; j <= qt; ++j) {
    __syncthreads();
    #pragma unroll
    for (int c = 0; c < 6; ++c) *(bf16x8*)(kdst + c * 2048) = kreg[c];
    #pragma unroll
    for (int c = 0; c < 4; ++c) *(bf16x8*)(vdst + c * 8) = vreg[c];
    __syncthreads();
    if (j < qt) {
      const bf16* src = ksrc + (size_t)(j + 1) * 64 * QKD;
      #pragma unroll
      for (int c = 0; c < 6; ++c) kreg[c] = ld8(src + c * 32);
      const bf16* vs2 = vsrc + (size_t)(j + 1) * 64;
      #pragma unroll
      for (int c = 0; c < 4; ++c) vreg[c] = ld8(vs2 + c * 8);
    }
    const int kc = j * 64;

    f32x4 S[4];
    #pragma unroll
    for (int nt = 0; nt < 4; ++nt) S[nt] = (f32x4){0.f, 0.f, 0.f, 0.f};
    #pragma unroll
    for (int c = 0; c < 6; ++c) {
      #pragma unroll
      for (int nt = 0; nt < 4; ++nt) {
        const bf16x8 kf = ld8(Ks + c * 2048 + (nt * 16 + l15) * 32 + qs);
        S[nt] = mfma16(qf[c], kf, S[nt]);
      }
    }

    float mnew[4] = {-1e30f, -1e30f, -1e30f, -1e30f};
    if (j == qt) {
      #pragma unroll
      for (int nt = 0; nt < 4; ++nt) {
        const int col = kc + nt * 16 + l15;
        #pragma unroll
        for (int r = 0; r < 4; r++) {
          const int row = r0 + quad * 4 + r;
          const float v = (col <= row) ? S[nt][r] * SM_SCALE : -1e30f;
          S[nt][r] = v;
          mnew[r] = fmaxf(mnew[r], v);
        }
      }
    } else {
      #pragma unroll
      for (int nt = 0; nt < 4; ++nt)
        #pragma unroll
        for (int r = 0; r < 4; r++) {
          const float v = S[nt][r] * SM_SCALE;
          S[nt][r] = v;
          mnew[r] = fmaxf(mnew[r], v);
        }
    }
    #pragma unroll
    for (int m = 8; m >= 1; m >>= 1)
      #pragma unroll
      for (int r = 0; r < 4; r++)
        mnew[r] = fmaxf(mnew[r], __shfl_xor(mnew[r], m, 64));
    float alpha[4], ladd[4] = {0.f, 0.f, 0.f, 0.f};
    #pragma unroll
    for (int r = 0; r < 4; r++) {
      const float mi = fmaxf(mrow[r], mnew[r]);
      alpha[r] = __expf(mrow[r] - mi);
      mrow[r] = mi;
    }
    #pragma unroll
    for (int nt = 0; nt < 4; ++nt)
      #pragma unroll
      for (int r = 0; r < 4; r++) {
        const float pv = __expf(S[nt][r] - mrow[r]);
        S[nt][r] = pv;
        ladd[r] += pv;
      }
    #pragma unroll
    for (int m = 8; m >= 1; m >>= 1)
      #pragma unroll
      for (int r = 0; r < 4; r++) ladd[r] += __shfl_xor(ladd[r], m, 64);
    #pragma unroll
    for (int r = 0; r < 4; r++) lrow[r] = lrow[r] * alpha[r] + ladd[r];
    #pragma unroll
    for (int d = 0; d < 8; ++d)
      #pragma unroll
      for (int r = 0; r < 4; r++) O[d][r] *= alpha[r];

    #pragma unroll
    for (int nt = 0; nt < 4; ++nt)
      #pragma unroll
      for (int r = 0; r < 4; r++)
        Plds[wave][quad * 4 + r][nt * 16 + l15] = __float2bfloat16(S[nt][r]);

    #pragma unroll
    for (int kt = 0; kt < 2; ++kt) {
      const bf16x8 pf = ld8(&Plds[wave][l15][kt * 32 + quad * 8]);
      #pragma unroll
      for (int dt = 0; dt < 8; ++dt) {
        const bf16x8 vf = ld8(Vs + (dt * 16 + l15) * 72 + kt * 32 + quad * 8);
        O[dt] = mfma16(pf, vf, O[dt]);
      }
    }
  }

  #pragma unroll
  for (int dt = 0; dt < 8; ++dt) {
    const int col = head * VD + dt * 16 + l15;
    #pragma unroll
    for (int r = 0; r < 4; r++) {
      const int row = r0 + quad * 4 + r;
      aout[(size_t)row * (NHEADS * VD) + col] = __float2bfloat16(O[dt][r] / lrow[r]);
    }
  }
}

// ---------------- host orchestration ----------------
extern "C" void kernel_launch(void* const* d_in, const int* in_sizes, int n_in,
                              void* d_out, int out_size, void* d_ws, size_t ws_size,
                              hipStream_t stream)
{
  const float* hs      = (const float*)d_in[0];
  const int*   pos     = (const int*)  d_in[1];
  const float* ln_w    = (const float*)d_in[3];
  const float* wq_a    = (const float*)d_in[4];
  const float* q_a_ln  = (const float*)d_in[5];
  const float* wq_b    = (const float*)d_in[6];
  const float* wkv_a   = (const float*)d_in[7];
  const float* kv_a_ln = (const float*)d_in[8];
  const float* wkv_b   = (const float*)d_in[9];
  const float* wo      = (const float*)d_in[10];

  float* out_hidden = (float*)d_out;
  float* out_k = out_hidden + (size_t)S_LEN * HIDDEN;
  float* out_v = out_k + (size_t)NHEADS * S_LEN * QKD;

  char* ws = (char*)d_ws;
  size_t off = 0;
  auto alloc = [&](size_t bytes) { char* p = ws + off; off += (bytes + 255) & ~255ULL; return p; };

  bf16* h_b     = (bf16*)alloc((size_t)S_LEN * HIDDEN * 2);
  bf16* w1_b    = (bf16*)alloc((size_t)QCKN * HIDDEN * 2);
  bf16* wqb_b   = (bf16*)alloc((size_t)QN * QLORA * 2);
  bf16* wkvb_b  = (bf16*)alloc((size_t)KVN * KVLORA * 2);
  bf16* wo_b    = (bf16*)alloc((size_t)HIDDEN * (NHEADS * VD) * 2);
  // scratch region reused twice:
  //   phase 1: gemm1 partials [4][S][2112] fp32            (69.2 MB)
  //   phase 2: q partials [2][S][3072] fp32 + kv_f [S][4096] fp32 (83.9 MB)
  char* region  = alloc((size_t)2 * S_LEN * QN * 4 + (size_t)S_LEN * KVN * 4);
  float* qa_parts = (float*)region;
  float* q_f      = (float*)region;                       // alias (after rmsnorm2)
  float* kv_f     = (float*)(region + (size_t)2 * S_LEN * QN * 4);
  float* kpe_sum = (float*)alloc((size_t)S_LEN * 64 * 4);
  bf16* qa_n    = (bf16*)alloc((size_t)S_LEN * QLORA * 2);
  bf16* ckv_n   = (bf16*)alloc((size_t)S_LEN * KVLORA * 2);
  bf16* q_bf    = (bf16*)alloc((size_t)NHEADS * S_LEN * QKD * 2);
  bf16* k_bf    = (bf16*)alloc((size_t)NHEADS * S_LEN * QKD * 2);
  bf16* vt_bf   = (bf16*)alloc((size_t)NHEADS * VD * S_LEN * 2);
  bf16* attn_b  = (bf16*)alloc((size_t)S_LEN * (NHEADS * VD) * 2);

  {
    const int n0 = (QLORA * HIDDEN) / 4;
    const int n1 = ((QCKN - QLORA) * HIDDEN) / 4;
    const int n2 = (QN * QLORA) / 4;
    const int n3 = (KVN * KVLORA) / 4;
    const int n4s = (HIDDEN * NHEADS * VD) / 4;
    const int tot = n0 + n1 + n2 + n3 + n4s;
    cvt_multi<<<(tot + 255) / 256, 256, 0, stream>>>(
        wq_a, w1_b, n0,
        wkv_a, w1_b + (size_t)QLORA * HIDDEN, n1,
        wq_b, wqb_b, n2,
        wkv_b, wkvb_b, n3,
        wo, wo_b, n4s);
  }

  rmsnorm_k<<<S_LEN, 256, 0, stream>>>(hs, HIDDEN, HIDDEN, ln_w, h_b, HIDDEN);

  // gemm1: [qa|ckv|kpe] partials = h @ w1^T  (split-K x4 -> 1088 blocks,
  // klen=1280, disjoint partial outputs, plain stores)
  gemm_nt<false, true, true><<<dim3(16, 17, 4), 256, 0, stream>>>(
      h_b, w1_b, qa_parts, S_LEN, QCKN, HIDDEN, HIDDEN / 4, nullptr, 0.f);

  // fused dual rmsnorm + 4-way partial reduction + kpe extraction
  rmsnorm2_k<<<2 * S_LEN, 256, 0, stream>>>(qa_parts, q_a_ln, kv_a_ln,
                                            qa_n, ckv_n, kpe_sum);

  // q partials = qa_n @ wq_b^T (split-K x2 -> 768 blocks, klen=768; reduction
  // fused into rope_assemble). Overwrites qa_parts region (dead now).
  gemm_nt<false, false, true><<<dim3(16, QN / 128, 2), 256, 0, stream>>>(
      qa_n, wqb_b, q_f, S_LEN, QN, QLORA, QLORA / 2, nullptr, 0.f);
  // kv = ckv_n @ wkv_b^T  (512 blocks, klen=512, plain store)
  gemm_nt<false, false, false><<<dim3(16, KVN / 128, 1), 256, 0, stream>>>(
      ckv_n, wkvb_b, kv_f, S_LEN, KVN, KVLORA, KVLORA, nullptr, 0.f);

  rope_assemble_k<<<S_LEN, 256, 0, stream>>>(q_f, kpe_sum, kv_f, pos,
                                             out_k, q_bf, k_bf);
  v_transpose_k<<<dim3(NHEADS, S_LEN / 32, VD / 32), 256, 0, stream>>>(kv_f, out_v, vt_bf);

  attn_k<<<dim3(S_LEN / 64, NHEADS), 256, 0, stream>>>(q_bf, k_bf, vt_bf, attn_b);

  // gemm4: out = attn @ wo^T + hs*0.125  (640 blocks, klen=2048, plain store)
  gemm_nt<true, false, false><<<dim3(16, HIDDEN / 128, 1), 256, 0, stream>>>(
      attn_b, wo_b, out_hidden, S_LEN, HIDDEN, NHEADS * VD, NHEADS * VD, hs, 0.125f);

  (void)in_sizes; (void)n_in; (void)out_size; (void)ws_size;
}